// Round 1
// baseline (783.191 us; speedup 1.0000x reference)
//
#include <hip/hip_runtime.h>

#define B_ 4
#define N_ 8192
#define DIN 64
#define HDIM 64
#define DOUT 128
#define KNN 16
#define QPB 64            // queries per block
#define TILE 512          // candidate tile staged in LDS
#define PART 4            // threads per query
#define CHUNK (TILE/PART) // candidates per thread per tile
#define NTILES (N_/TILE)
#define BLOCKS_PER_B (N_/QPB) // 128

// ---------------- K0: compose the 3 affine layers into A,B,C,D ----------------
// h3 = pos @ M3^T + bc,  M3 = w3@w2@w1 [64,10], bc = w3@(w2@b1+b2)+b3
// pos = [center(3), knn(3), diff(3), dsq]; diff = knn - center =>
//   A[o] = M3[o,0:3]-M3[o,6:9], B[o] = M3[o,3:6]+M3[o,6:9], C[o]=M3[o,9], D[o]=bc[o]
// prm layout: float4 prm[0..63] = (Ax,Ay,Az,D); prm[64..127] = (Bx,By,Bz,C)
__global__ __launch_bounds__(64) void k_params(
    const float* __restrict__ w1, const float* __restrict__ b1,
    const float* __restrict__ w2, const float* __restrict__ b2,
    const float* __restrict__ w3, const float* __restrict__ b3,
    float4* __restrict__ prm) {
  __shared__ float M2[HDIM][10];
  __shared__ float bb[HDIM];
  const int o = threadIdx.x;
  float r[10];
#pragma unroll
  for (int c = 0; c < 10; c++) r[c] = 0.f;
  float s = b2[o];
  for (int l = 0; l < HDIM; l++) {
    float w = w2[o * HDIM + l];
#pragma unroll
    for (int c = 0; c < 10; c++) r[c] = fmaf(w, w1[l * 10 + c], r[c]);
    s = fmaf(w, b1[l], s);
  }
#pragma unroll
  for (int c = 0; c < 10; c++) M2[o][c] = r[c];
  bb[o] = s;
  __syncthreads();
  float r3[10];
#pragma unroll
  for (int c = 0; c < 10; c++) r3[c] = 0.f;
  float bc = b3[o];
  for (int l = 0; l < HDIM; l++) {
    float w = w3[o * HDIM + l];
#pragma unroll
    for (int c = 0; c < 10; c++) r3[c] = fmaf(w, M2[l][c], r3[c]);
    bc = fmaf(w, bb[l], bc);
  }
  prm[o]      = make_float4(r3[0] - r3[6], r3[1] - r3[7], r3[2] - r3[8], bc);
  prm[64 + o] = make_float4(r3[3] + r3[6], r3[4] + r3[7], r3[5] + r3[8], r3[9]);
}

// replace-max insert into unsorted top-16 kept in registers (fully unrolled)
#define INSERT16(VARR, IARR, VMAX, DVAL, MIDX)                    \
  {                                                               \
    bool done = false;                                            \
    _Pragma("unroll") for (int _i = 0; _i < KNN; _i++) {          \
      bool hit = (!done) && (VARR[_i] == VMAX);                   \
      if (hit) { VARR[_i] = (DVAL); IARR[_i] = (MIDX); }          \
      done = done | hit;                                          \
    }                                                             \
    float _a = fmaxf(fmaxf(fmaxf(VARR[0], VARR[1]), fmaxf(VARR[2], VARR[3])),   \
                     fmaxf(fmaxf(VARR[4], VARR[5]), fmaxf(VARR[6], VARR[7])));  \
    float _b = fmaxf(fmaxf(fmaxf(VARR[8], VARR[9]), fmaxf(VARR[10], VARR[11])), \
                     fmaxf(fmaxf(VARR[12], VARR[13]), fmaxf(VARR[14], VARR[15])));\
    VMAX = fmaxf(_a, _b);                                         \
  }

// ---------------- K1: kNN + fe ----------------
__global__ __launch_bounds__(256) void k_knn_fe(
    const float* __restrict__ xyz, const float4* __restrict__ prm,
    float* __restrict__ feBuf) {
  const int blk = blockIdx.x;
  const int b  = blk / BLOCKS_PER_B;
  const int n0 = (blk % BLOCKS_PER_B) * QPB;
  const int t = threadIdx.x;
  const int q = t & 63;
  const int j = t >> 6;
  const float* xb = xyz + (size_t)b * 3 * N_;

  __shared__ float4 s4[TILE];                 // candidate tile (x,y,z,sq)
  __shared__ float qxs[QPB], qys[QPB], qzs[QPB], qss[QPB];
  __shared__ unsigned tau[QPB];               // shared per-query prune threshold
  __shared__ float mval[PART * KNN][QPB];     // merge buffer / later neighbor stage
  __shared__ int   midx[PART * KNN][QPB];
  __shared__ float4 prmL[2 * HDIM];

  if (t < QPB) {
    int n = n0 + t;
    float x = xb[n], y = xb[N_ + n], z = xb[2 * N_ + n];
    qxs[t] = x; qys[t] = y; qzs[t] = z;
    qss[t] = __fadd_rn(__fadd_rn(__fmul_rn(x, x), __fmul_rn(y, y)), __fmul_rn(z, z));
    tau[t] = 0x7f800000u;  // +inf
  }
  for (int i = t; i < 2 * HDIM; i += 256) prmL[i] = prm[i];

  const float INF = __uint_as_float(0x7f800000u);
  float v[KNN]; int id[KNN];
#pragma unroll
  for (int i = 0; i < KNN; i++) { v[i] = INF; id[i] = 0; }
  float vmax = INF;
  __syncthreads();
  const float qx = qxs[q], qy = qys[q], qz = qzs[q], qs = qss[q];

  for (int tl = 0; tl < NTILES; tl++) {
    const int base = tl * TILE;
#pragma unroll
    for (int r = 0; r < TILE; r += 256) {
      int m = base + r + t;
      float x = xb[m], y = xb[N_ + m], z = xb[2 * N_ + m];
      s4[r + t] = make_float4(
          x, y, z,
          __fadd_rn(__fadd_rn(__fmul_rn(x, x), __fmul_rn(y, y)), __fmul_rn(z, z)));
    }
    __syncthreads();
    float gate = fminf(vmax, __uint_as_float(tau[q]));
    const int m0 = base + j * CHUNK;
    for (int u = 0; u < CHUNK; u++) {
      float4 c = s4[j * CHUNK + u];
      // match reference rounding: dot as fma chain, sq/sum as plain mul+add
      float dot = fmaf(c.z, qz, fmaf(c.y, qy, __fmul_rn(c.x, qx)));
      float d = __fsub_rn(__fadd_rn(qs, c.w), __fmul_rn(2.0f, dot));
      if (d < gate) {
        int m = m0 + u;
        INSERT16(v, id, vmax, d, m);
        gate = fminf(vmax, gate);
      }
    }
    atomicMin(&tau[q], __float_as_uint(vmax));
    __syncthreads();
  }

  // merge 4 partial lists -> final top-16 per query
#pragma unroll
  for (int i = 0; i < KNN; i++) { mval[j * KNN + i][q] = v[i]; midx[j * KNN + i][q] = id[i]; }
  __syncthreads();
  if (t < QPB) {
    float fv[KNN]; int fid[KNN];
#pragma unroll
    for (int i = 0; i < KNN; i++) { fv[i] = INF; fid[i] = 0; }
    float fm = INF;
    for (int s = 0; s < PART * KNN; s++) {
      float d = mval[s][q];
      if (d < fm) {
        int m = midx[s][q];
        INSERT16(fv, fid, fm, d, m);
      }
    }
#pragma unroll
    for (int i = 0; i < KNN; i++) midx[i][q] = fid[i];
  }
  __syncthreads();

  // gather neighbor coords + dsq into LDS (reuse mval area), 4 per thread
#pragma unroll
  for (int kk = 0; kk < KNN / PART; kk++) {
    int k = j * (KNN / PART) + kk;
    int m = midx[k][q];
    float x = xb[m], y = xb[N_ + m], z = xb[2 * N_ + m];
    float dx = __fsub_rn(x, qx), dy = __fsub_rn(y, qy), dz = __fsub_rn(z, qz);
    float dsq = __fadd_rn(__fadd_rn(__fmul_rn(dx, dx), __fmul_rn(dy, dy)),
                          __fmul_rn(dz, dz));
    mval[k][q] = x; mval[KNN + k][q] = y; mval[2 * KNN + k][q] = z;
    mval[3 * KNN + k][q] = dsq;
  }
  __syncthreads();

  float nx[KNN], ny[KNN], nz[KNN], nd[KNN];
#pragma unroll
  for (int k = 0; k < KNN; k++) {
    nx[k] = mval[k][q]; ny[k] = mval[KNN + k][q];
    nz[k] = mval[2 * KNN + k][q]; nd[k] = mval[3 * KNN + k][q];
  }
  float fo[16];
#pragma unroll
  for (int oi = 0; oi < 16; oi++) {
    int o = j * 16 + oi;
    float4 pA = prmL[o], pB = prmL[HDIM + o];
    float basev = fmaf(qz, pA.z, fmaf(qy, pA.y, fmaf(qx, pA.x, pA.w)));
    float mx = -INF;
#pragma unroll
    for (int k = 0; k < KNN; k++) {
      float tv = fmaf(nz[k], pB.z,
                 fmaf(ny[k], pB.y,
                 fmaf(nx[k], pB.x, __fmul_rn(nd[k], pB.w))));
      mx = fmaxf(mx, tv);
    }
    fo[oi] = basev + mx;
  }
  float* feRow = feBuf + (size_t)(b * N_ + n0 + q) * HDIM;
  float4* feV = (float4*)(feRow + j * 16);
#pragma unroll
  for (int w = 0; w < 4; w++)
    feV[w] = make_float4(fo[4 * w], fo[4 * w + 1], fo[4 * w + 2], fo[4 * w + 3]);
}

// ---------------- K2: shortcut GEMM + combine ----------------
__global__ __launch_bounds__(256) void k_out(
    const float* __restrict__ feature, const float* __restrict__ wsM,
    const float* __restrict__ bs, const float* __restrict__ feBuf,
    float* __restrict__ out) {
  const int blk = blockIdx.x;
  const int b  = blk / BLOCKS_PER_B;
  const int n0 = (blk % BLOCKS_PER_B) * QPB;
  const int t = threadIdx.x;
  const int q = t & 63;
  const int jj = t >> 6;
  __shared__ float featL[DIN][QPB];  // 16 KB
  __shared__ float wsL[DOUT][DIN];   // 32 KB
#pragma unroll
  for (int r = 0; r < DIN; r += PART) {
    int c = r + jj;
    featL[c][q] = feature[(size_t)(b * DIN + c) * N_ + n0 + q];
  }
  for (int i = t; i < DOUT * DIN; i += 256) ((float*)wsL)[i] = wsM[i];
  __syncthreads();
  float f[DIN];
#pragma unroll
  for (int c = 0; c < DIN; c++) f[c] = featL[c][q];
  const float* feRow = feBuf + (size_t)(b * N_ + n0 + q) * HDIM;
  const int o0 = jj * 32;
  for (int oi = 0; oi < 32; oi++) {
    int o = o0 + oi;
    const float4* wr = (const float4*)wsL[o];
    float acc = 0.f;
#pragma unroll
    for (int c4 = 0; c4 < DIN / 4; c4++) {
      float4 w = wr[c4];
      acc = fmaf(w.x, f[4 * c4], acc);
      acc = fmaf(w.y, f[4 * c4 + 1], acc);
      acc = fmaf(w.z, f[4 * c4 + 2], acc);
      acc = fmaf(w.w, f[4 * c4 + 3], acc);
    }
    float r = acc + bs[o] + feRow[o & 63];
    out[(size_t)(b * DOUT + o) * N_ + n0 + q] = r;
  }
}

extern "C" void kernel_launch(void* const* d_in, const int* in_sizes, int n_in,
                              void* d_out, int out_size, void* d_ws, size_t ws_size,
                              hipStream_t stream) {
  const float* xyz     = (const float*)d_in[0];
  const float* feature = (const float*)d_in[1];
  const float* w1 = (const float*)d_in[2];
  const float* b1 = (const float*)d_in[3];
  const float* w2 = (const float*)d_in[4];
  const float* b2 = (const float*)d_in[5];
  const float* w3 = (const float*)d_in[6];
  const float* b3 = (const float*)d_in[7];
  const float* wsM = (const float*)d_in[8];
  const float* bs  = (const float*)d_in[9];
  float* out = (float*)d_out;

  // workspace: [0,2KB) composed params, [4KB, 4KB+8MB) fe buffer
  float4* prm  = (float4*)d_ws;
  float* feBuf = (float*)((char*)d_ws + 4096);

  hipLaunchKernelGGL(k_params, dim3(1), dim3(64), 0, stream,
                     w1, b1, w2, b2, w3, b3, prm);
  hipLaunchKernelGGL(k_knn_fe, dim3(B_ * BLOCKS_PER_B), dim3(256), 0, stream,
                     xyz, prm, feBuf);
  hipLaunchKernelGGL(k_out, dim3(B_ * BLOCKS_PER_B), dim3(256), 0, stream,
                     feature, wsM, bs, feBuf, out);
}

// Round 2
// 438.387 us; speedup vs baseline: 1.7865x; 1.7865x over previous
//
#include <hip/hip_runtime.h>

#define B_ 4
#define N_ 8192
#define DIN 64
#define HDIM 64
#define DOUT 128
#define KNN 16
#define QPB 64            // queries per block
#define TILE 512          // candidate tile staged in LDS
#define PART 4            // threads per query
#define CHUNK (TILE/PART) // candidates per thread per tile
#define NTILES (N_/TILE)
#define BLOCKS_PER_B (N_/QPB) // 128
#define CAP 16            // deferred-insert buffer slots per thread

// ---------------- K0: compose the 3 affine layers into A,B,C,D ----------------
// h3 = pos @ M3^T + bc,  M3 = w3@w2@w1 [64,10], bc = w3@(w2@b1+b2)+b3
// pos = [center(3), knn(3), diff(3), dsq]; diff = knn - center =>
//   A[o] = M3[o,0:3]-M3[o,6:9], B[o] = M3[o,3:6]+M3[o,6:9], C[o]=M3[o,9], D[o]=bc[o]
// prm layout: float4 prm[0..63] = (Ax,Ay,Az,D); prm[64..127] = (Bx,By,Bz,C)
__global__ __launch_bounds__(64) void k_params(
    const float* __restrict__ w1, const float* __restrict__ b1,
    const float* __restrict__ w2, const float* __restrict__ b2,
    const float* __restrict__ w3, const float* __restrict__ b3,
    float4* __restrict__ prm) {
  __shared__ float M2[HDIM][10];
  __shared__ float bb[HDIM];
  const int o = threadIdx.x;
  float r[10];
#pragma unroll
  for (int c = 0; c < 10; c++) r[c] = 0.f;
  float s = b2[o];
  for (int l = 0; l < HDIM; l++) {
    float w = w2[o * HDIM + l];
#pragma unroll
    for (int c = 0; c < 10; c++) r[c] = fmaf(w, w1[l * 10 + c], r[c]);
    s = fmaf(w, b1[l], s);
  }
#pragma unroll
  for (int c = 0; c < 10; c++) M2[o][c] = r[c];
  bb[o] = s;
  __syncthreads();
  float r3[10];
#pragma unroll
  for (int c = 0; c < 10; c++) r3[c] = 0.f;
  float bc = b3[o];
  for (int l = 0; l < HDIM; l++) {
    float w = w3[o * HDIM + l];
#pragma unroll
    for (int c = 0; c < 10; c++) r3[c] = fmaf(w, M2[l][c], r3[c]);
    bc = fmaf(w, bb[l], bc);
  }
  prm[o]      = make_float4(r3[0] - r3[6], r3[1] - r3[7], r3[2] - r3[8], bc);
  prm[64 + o] = make_float4(r3[3] + r3[6], r3[4] + r3[7], r3[5] + r3[8], r3[9]);
}

// replace-max insert into unsorted top-16 kept in registers (fully unrolled)
#define INSERT16(VARR, IARR, VMAX, DVAL, MIDX)                    \
  {                                                               \
    bool done = false;                                            \
    _Pragma("unroll") for (int _i = 0; _i < KNN; _i++) {          \
      bool hit = (!done) && (VARR[_i] == VMAX);                   \
      if (hit) { VARR[_i] = (DVAL); IARR[_i] = (MIDX); }          \
      done = done | hit;                                          \
    }                                                             \
    float _a = fmaxf(fmaxf(fmaxf(VARR[0], VARR[1]), fmaxf(VARR[2], VARR[3])),   \
                     fmaxf(fmaxf(VARR[4], VARR[5]), fmaxf(VARR[6], VARR[7])));  \
    float _b = fmaxf(fmaxf(fmaxf(VARR[8], VARR[9]), fmaxf(VARR[10], VARR[11])), \
                     fmaxf(fmaxf(VARR[12], VARR[13]), fmaxf(VARR[14], VARR[15])));\
    VMAX = fmaxf(_a, _b);                                         \
  }

// process the deferred buffer through INSERT16, then tighten gate
#define FLUSH()                                                   \
  {                                                               \
    for (int c_ = 0; c_ < cnt; c_++) {                            \
      float fd_ = poolF[c_ * 256 + t];                            \
      int fm_ = poolI[c_ * 256 + t];                              \
      if (fd_ < vmax) { INSERT16(v, id, vmax, fd_, fm_); }        \
    }                                                             \
    cnt = 0;                                                      \
    atomicMin(&tau[q], __float_as_uint(vmax));                    \
    gate = fminf(vmax, __uint_as_float(tau[q]));                  \
  }

// ---------------- K1: kNN + fe ----------------
__global__ __launch_bounds__(256) void k_knn_fe(
    const float* __restrict__ xyz, const float4* __restrict__ prm,
    float* __restrict__ feBuf) {
  const int blk = blockIdx.x;
  const int b  = blk / BLOCKS_PER_B;
  const int n0 = (blk % BLOCKS_PER_B) * QPB;
  const int t = threadIdx.x;
  const int q = t & 63;
  const int j = t >> 6;
  const float* xb = xyz + (size_t)b * 3 * N_;

  __shared__ float4 s4[TILE];                 // candidate tile (x,y,z,sq)  8 KB
  __shared__ float qxs[QPB], qys[QPB], qzs[QPB], qss[QPB];
  __shared__ unsigned tau[QPB];               // shared per-query prune threshold
  __shared__ float4 prmL[2 * HDIM];
  // 32 KB pool, time-multiplexed:
  //   scan phase:  bufD[c][t]=poolF[c*256+t], bufI[c][t]=poolI[c*256+t]  (c<CAP)
  //   merge phase: mval[r][q]=poolF[r*64+q],  midx[r][q]=poolI[r*64+q]   (r<64)
  __shared__ float poolF[CAP * 256];
  __shared__ int   poolI[CAP * 256];

  if (t < QPB) {
    int n = n0 + t;
    float x = xb[n], y = xb[N_ + n], z = xb[2 * N_ + n];
    qxs[t] = x; qys[t] = y; qzs[t] = z;
    qss[t] = __fadd_rn(__fadd_rn(__fmul_rn(x, x), __fmul_rn(y, y)), __fmul_rn(z, z));
    tau[t] = 0x7f800000u;  // +inf
  }
  for (int i = t; i < 2 * HDIM; i += 256) prmL[i] = prm[i];

  const float INF = __uint_as_float(0x7f800000u);
  float v[KNN]; int id[KNN];
#pragma unroll
  for (int i = 0; i < KNN; i++) { v[i] = INF; id[i] = 0; }
  float vmax = INF;
  int cnt = 0;
  __syncthreads();
  const float qx = qxs[q], qy = qys[q], qz = qzs[q], qs = qss[q];

  for (int tl = 0; tl < NTILES; tl++) {
    const int base = tl * TILE;
#pragma unroll
    for (int r = 0; r < TILE; r += 256) {
      int m = base + r + t;
      float x = xb[m], y = xb[N_ + m], z = xb[2 * N_ + m];
      s4[r + t] = make_float4(
          x, y, z,
          __fadd_rn(__fadd_rn(__fmul_rn(x, x), __fmul_rn(y, y)), __fmul_rn(z, z)));
    }
    __syncthreads();
    float gate = fminf(vmax, __uint_as_float(tau[q]));
    const int m0 = base + j * CHUNK;
    for (int u = 0; u < CHUNK; u++) {
      float4 c = s4[j * CHUNK + u];
      // match reference rounding: dot as fma chain, sq/sum as plain mul+add
      float dot = fmaf(c.z, qz, fmaf(c.y, qy, __fmul_rn(c.x, qx)));
      float d = __fsub_rn(__fadd_rn(qs, c.w), __fmul_rn(2.0f, dot));
      if (d < gate) {                 // cheap predicated push (3 instrs)
        poolF[cnt * 256 + t] = d;
        poolI[cnt * 256 + t] = m0 + u;
        cnt++;
      }
      if (__any(cnt >= CAP)) {        // batched divergence: flush whole wave
        FLUSH();
      }
    }
    {
      FLUSH();                        // drain before tau publish / tile swap
    }
    __syncthreads();
  }

  __syncthreads();  // all flushes done before pool is reused for merge

  // merge 4 partial lists -> final top-16 per query  (pool as mval/midx)
#pragma unroll
  for (int i = 0; i < KNN; i++) {
    poolF[(j * KNN + i) * 64 + q] = v[i];
    poolI[(j * KNN + i) * 64 + q] = id[i];
  }
  __syncthreads();
  if (t < QPB) {
    float fv[KNN]; int fid[KNN];
#pragma unroll
    for (int i = 0; i < KNN; i++) { fv[i] = INF; fid[i] = 0; }
    float fm = INF;
    for (int s = 0; s < PART * KNN; s++) {
      float d = poolF[s * 64 + q];
      if (d < fm) {
        int m = poolI[s * 64 + q];
        INSERT16(fv, fid, fm, d, m);
      }
    }
#pragma unroll
    for (int i = 0; i < KNN; i++) poolI[i * 64 + q] = fid[i];
  }
  __syncthreads();

  // gather neighbor coords + dsq into LDS (poolF rows 0..63), 4 per thread
#pragma unroll
  for (int kk = 0; kk < KNN / PART; kk++) {
    int k = j * (KNN / PART) + kk;
    int m = poolI[k * 64 + q];
    float x = xb[m], y = xb[N_ + m], z = xb[2 * N_ + m];
    float dx = __fsub_rn(x, qx), dy = __fsub_rn(y, qy), dz = __fsub_rn(z, qz);
    float dsq = __fadd_rn(__fadd_rn(__fmul_rn(dx, dx), __fmul_rn(dy, dy)),
                          __fmul_rn(dz, dz));
    poolF[k * 64 + q] = x;
    poolF[(KNN + k) * 64 + q] = y;
    poolF[(2 * KNN + k) * 64 + q] = z;
    poolF[(3 * KNN + k) * 64 + q] = dsq;
  }
  __syncthreads();

  float nx[KNN], ny[KNN], nz[KNN], nd[KNN];
#pragma unroll
  for (int k = 0; k < KNN; k++) {
    nx[k] = poolF[k * 64 + q];
    ny[k] = poolF[(KNN + k) * 64 + q];
    nz[k] = poolF[(2 * KNN + k) * 64 + q];
    nd[k] = poolF[(3 * KNN + k) * 64 + q];
  }
  float fo[16];
#pragma unroll
  for (int oi = 0; oi < 16; oi++) {
    int o = j * 16 + oi;
    float4 pA = prmL[o], pB = prmL[HDIM + o];
    float basev = fmaf(qz, pA.z, fmaf(qy, pA.y, fmaf(qx, pA.x, pA.w)));
    float mx = -INF;
#pragma unroll
    for (int k = 0; k < KNN; k++) {
      float tv = fmaf(nz[k], pB.z,
                 fmaf(ny[k], pB.y,
                 fmaf(nx[k], pB.x, __fmul_rn(nd[k], pB.w))));
      mx = fmaxf(mx, tv);
    }
    fo[oi] = basev + mx;
  }
  float* feRow = feBuf + (size_t)(b * N_ + n0 + q) * HDIM;
  float4* feV = (float4*)(feRow + j * 16);
#pragma unroll
  for (int w = 0; w < 4; w++)
    feV[w] = make_float4(fo[4 * w], fo[4 * w + 1], fo[4 * w + 2], fo[4 * w + 3]);
}

// ---------------- K2: shortcut GEMM + combine ----------------
__global__ __launch_bounds__(256) void k_out(
    const float* __restrict__ feature, const float* __restrict__ wsM,
    const float* __restrict__ bs, const float* __restrict__ feBuf,
    float* __restrict__ out) {
  const int blk = blockIdx.x;
  const int b  = blk / BLOCKS_PER_B;
  const int n0 = (blk % BLOCKS_PER_B) * QPB;
  const int t = threadIdx.x;
  const int q = t & 63;
  const int jj = t >> 6;
  __shared__ float featL[DIN][QPB];  // 16 KB
  __shared__ float wsL[DOUT][DIN];   // 32 KB
#pragma unroll
  for (int r = 0; r < DIN; r += PART) {
    int c = r + jj;
    featL[c][q] = feature[(size_t)(b * DIN + c) * N_ + n0 + q];
  }
  for (int i = t; i < DOUT * DIN; i += 256) ((float*)wsL)[i] = wsM[i];
  __syncthreads();
  float f[DIN];
#pragma unroll
  for (int c = 0; c < DIN; c++) f[c] = featL[c][q];
  const float* feRow = feBuf + (size_t)(b * N_ + n0 + q) * HDIM;
  const int o0 = jj * 32;
  for (int oi = 0; oi < 32; oi++) {
    int o = o0 + oi;
    const float4* wr = (const float4*)wsL[o];
    float acc = 0.f;
#pragma unroll
    for (int c4 = 0; c4 < DIN / 4; c4++) {
      float4 w = wr[c4];
      acc = fmaf(w.x, f[4 * c4], acc);
      acc = fmaf(w.y, f[4 * c4 + 1], acc);
      acc = fmaf(w.z, f[4 * c4 + 2], acc);
      acc = fmaf(w.w, f[4 * c4 + 3], acc);
    }
    float r = acc + bs[o] + feRow[o & 63];
    out[(size_t)(b * DOUT + o) * N_ + n0 + q] = r;
  }
}

extern "C" void kernel_launch(void* const* d_in, const int* in_sizes, int n_in,
                              void* d_out, int out_size, void* d_ws, size_t ws_size,
                              hipStream_t stream) {
  const float* xyz     = (const float*)d_in[0];
  const float* feature = (const float*)d_in[1];
  const float* w1 = (const float*)d_in[2];
  const float* b1 = (const float*)d_in[3];
  const float* w2 = (const float*)d_in[4];
  const float* b2 = (const float*)d_in[5];
  const float* w3 = (const float*)d_in[6];
  const float* b3 = (const float*)d_in[7];
  const float* wsM = (const float*)d_in[8];
  const float* bs  = (const float*)d_in[9];
  float* out = (float*)d_out;

  // workspace: [0,2KB) composed params, [4KB, 4KB+8MB) fe buffer
  float4* prm  = (float4*)d_ws;
  float* feBuf = (float*)((char*)d_ws + 4096);

  hipLaunchKernelGGL(k_params, dim3(1), dim3(64), 0, stream,
                     w1, b1, w2, b2, w3, b3, prm);
  hipLaunchKernelGGL(k_knn_fe, dim3(B_ * BLOCKS_PER_B), dim3(256), 0, stream,
                     xyz, prm, feBuf);
  hipLaunchKernelGGL(k_out, dim3(B_ * BLOCKS_PER_B), dim3(256), 0, stream,
                     feature, wsM, bs, feBuf, out);
}

// Round 3
// 301.597 us; speedup vs baseline: 2.5968x; 1.4536x over previous
//
#include <hip/hip_runtime.h>

#define B_ 4
#define N_ 8192
#define DIN 64
#define HDIM 64
#define DOUT 128
#define KNN 16
#define QPB 64               // queries per block (= lanes per wave)
#define PART 8               // partner waves per query block
#define NTHR (QPB * PART)    // 512 threads / block
#define CHUNK (N_ / PART)    // 1024 candidates per thread
#define CAP 16               // deferred-insert buffer slots per thread
#define BLOCKS_PER_B (N_ / QPB)  // 128

// ---------------- K_prep: pack (x,y,z,sq) + compose affine params ----------------
// pk[b*8192+m] = (x,y,z, x*x+y*y+z*z)   [sq rounding matches reference]
// prm[0..63] = (Ax,Ay,Az,D); prm[64..127] = (Bx,By,Bz,C) where
//   M3 = w3@w2@w1, bc = w3@(w2@b1+b2)+b3,
//   A = M3[:,0:3]-M3[:,6:9], B = M3[:,3:6]+M3[:,6:9], C = M3[:,9], D = bc
__global__ __launch_bounds__(256) void k_prep(
    const float* __restrict__ xyz,
    const float* __restrict__ w1, const float* __restrict__ b1,
    const float* __restrict__ w2, const float* __restrict__ b2,
    const float* __restrict__ w3, const float* __restrict__ b3,
    float4* __restrict__ pk, float4* __restrict__ prm) {
  const int blk = blockIdx.x, t = threadIdx.x;
  const int b = blk >> 5;
  const int m = ((blk & 31) << 8) + t;
  const float* xb = xyz + (size_t)b * 3 * N_;
  float x = xb[m], y = xb[N_ + m], z = xb[2 * N_ + m];
  float sq = __fadd_rn(__fadd_rn(__fmul_rn(x, x), __fmul_rn(y, y)), __fmul_rn(z, z));
  pk[((size_t)b << 13) + m] = make_float4(x, y, z, sq);

  if (blk == 0) {
    __shared__ float M2[HDIM][10];
    __shared__ float bb[HDIM];
    const int o = t;
    if (o < HDIM) {
      float r[10];
#pragma unroll
      for (int c = 0; c < 10; c++) r[c] = 0.f;
      float s = b2[o];
      for (int l = 0; l < HDIM; l++) {
        float w = w2[o * HDIM + l];
#pragma unroll
        for (int c = 0; c < 10; c++) r[c] = fmaf(w, w1[l * 10 + c], r[c]);
        s = fmaf(w, b1[l], s);
      }
#pragma unroll
      for (int c = 0; c < 10; c++) M2[o][c] = r[c];
      bb[o] = s;
    }
    __syncthreads();
    if (o < HDIM) {
      float r3[10];
#pragma unroll
      for (int c = 0; c < 10; c++) r3[c] = 0.f;
      float bc = b3[o];
      for (int l = 0; l < HDIM; l++) {
        float w = w3[o * HDIM + l];
#pragma unroll
        for (int c = 0; c < 10; c++) r3[c] = fmaf(w, M2[l][c], r3[c]);
        bc = fmaf(w, bb[l], bc);
      }
      prm[o]      = make_float4(r3[0] - r3[6], r3[1] - r3[7], r3[2] - r3[8], bc);
      prm[64 + o] = make_float4(r3[3] + r3[6], r3[4] + r3[7], r3[5] + r3[8], r3[9]);
    }
  }
}

// replace-max insert into unsorted top-16 kept in registers (fully unrolled)
#define INSERT16(VARR, IARR, VMAX, DVAL, MIDX)                    \
  {                                                               \
    bool done = false;                                            \
    _Pragma("unroll") for (int _i = 0; _i < KNN; _i++) {          \
      bool hit = (!done) && (VARR[_i] == VMAX);                   \
      if (hit) { VARR[_i] = (DVAL); IARR[_i] = (MIDX); }          \
      done = done | hit;                                          \
    }                                                             \
    float _a = fmaxf(fmaxf(fmaxf(VARR[0], VARR[1]), fmaxf(VARR[2], VARR[3])),   \
                     fmaxf(fmaxf(VARR[4], VARR[5]), fmaxf(VARR[6], VARR[7])));  \
    float _b = fmaxf(fmaxf(fmaxf(VARR[8], VARR[9]), fmaxf(VARR[10], VARR[11])), \
                     fmaxf(fmaxf(VARR[12], VARR[13]), fmaxf(VARR[14], VARR[15])));\
    VMAX = fmaxf(_a, _b);                                         \
  }

#define MAX16(VARR, VMAX)                                         \
  {                                                               \
    float _a = fmaxf(fmaxf(fmaxf(VARR[0], VARR[1]), fmaxf(VARR[2], VARR[3])),   \
                     fmaxf(fmaxf(VARR[4], VARR[5]), fmaxf(VARR[6], VARR[7])));  \
    float _b = fmaxf(fmaxf(fmaxf(VARR[8], VARR[9]), fmaxf(VARR[10], VARR[11])), \
                     fmaxf(fmaxf(VARR[12], VARR[13]), fmaxf(VARR[14], VARR[15])));\
    VMAX = fmaxf(_a, _b);                                         \
  }

// drain deferred buffer through INSERT16, publish tau, tighten gate
#define FLUSH()                                                   \
  {                                                               \
    for (int c_ = 0; c_ < cnt; c_++) {                            \
      float fd_ = poolF[c_ * NTHR + t];                           \
      int fm_ = poolI[c_ * NTHR + t];                             \
      if (fd_ < vmax) { INSERT16(v, id, vmax, fd_, fm_); }        \
    }                                                             \
    cnt = 0;                                                      \
    atomicMin(&tau[q], __float_as_uint(vmax));                    \
    gate = fminf(vmax, __uint_as_float(tau[q]));                  \
  }

// ---------------- K1: kNN + fe ----------------
// block: 64 queries x 8 partner waves; wave j scans candidates [j*1024,(j+1)*1024)
// via wave-uniform global_load_dwordx4 from the packed pk array (L2-resident).
__global__ __launch_bounds__(512, 4) void k_knn_fe(
    const float4* __restrict__ pk, const float4* __restrict__ prm,
    float* __restrict__ feBuf) {
  const int blk = blockIdx.x;
  const int b  = blk / BLOCKS_PER_B;
  const int n0 = (blk % BLOCKS_PER_B) * QPB;
  const int t = threadIdx.x;
  const int q = t & 63;
  const int j = __builtin_amdgcn_readfirstlane(t >> 6);  // wave-uniform partner id

  __shared__ unsigned tau[QPB];
  __shared__ float4 prmL[2 * HDIM];
  // 48 KB pool, time-multiplexed:
  //  scan:   poolF[c*512+t], poolI[c*512+t]            (c < CAP)
  //  merge:  rows r<128: poolF[r*64+q], poolI[r*64+q]
  //  gather: rows r<64 of poolF = neighbor x/y/z/dsq
  __shared__ float poolF[CAP * NTHR];
  __shared__ unsigned short poolI[CAP * NTHR];

  if (t < QPB) tau[t] = 0x7f800000u;  // +inf
  for (int i = t; i < 2 * HDIM; i += NTHR) prmL[i] = prm[i];

  // query point (per lane, read from packed array)
  const float4 qv = pk[((size_t)b << 13) + n0 + q];
  const float qx = qv.x, qy = qv.y, qz = qv.z, qs = qv.w;

  const float INF = __uint_as_float(0x7f800000u);
  float v[KNN]; int id[KNN];
#pragma unroll
  for (int i = 0; i < KNN; i++) { v[i] = INF; id[i] = 0; }
  float vmax = INF, gate = INF;
  int cnt = 0;
  __syncthreads();

  const float4* pj = pk + ((size_t)b << 13) + j * CHUNK;
  for (int u0 = 0; u0 < CHUNK; u0 += 8) {
    if (__any(cnt > CAP - 8)) { FLUSH(); }
    gate = fminf(gate, __uint_as_float(tau[q]));  // pick up partners' progress
    float4 c[8];
#pragma unroll
    for (int e = 0; e < 8; e++) c[e] = pj[u0 + e];  // 8 independent uniform loads
#pragma unroll
    for (int e = 0; e < 8; e++) {
      // match reference rounding: dot as fma chain, sums as plain mul+add
      float dot = fmaf(c[e].z, qz, fmaf(c[e].y, qy, __fmul_rn(c[e].x, qx)));
      float d = __fsub_rn(__fadd_rn(qs, c[e].w), __fmul_rn(2.0f, dot));
      if (d < gate) {  // cheap predicated push
        poolF[cnt * NTHR + t] = d;
        poolI[cnt * NTHR + t] = (unsigned short)(j * CHUNK + u0 + e);
        cnt++;
      }
    }
  }
  FLUSH();
  __syncthreads();

  // publish per-thread lists: rows j*16+i (ascending-m order across j)
#pragma unroll
  for (int i = 0; i < KNN; i++) {
    poolF[(j * KNN + i) * QPB + q] = v[i];
    poolI[(j * KNN + i) * QPB + q] = (unsigned short)id[i];
  }
  __syncthreads();

  // stage A: thread (q, j<4) merges partners 2j and 2j+1 -> rows (2j)*16..+15
  float fv[KNN]; int fid[KNN]; float fm = INF;
  if (j < 4) {
    const int r0 = (2 * j) * KNN, r1 = (2 * j + 1) * KNN;
#pragma unroll
    for (int i = 0; i < KNN; i++) {
      fv[i] = poolF[(r0 + i) * QPB + q];
      fid[i] = poolI[(r0 + i) * QPB + q];
    }
    MAX16(fv, fm);
    for (int s = 0; s < KNN; s++) {
      float d = poolF[(r1 + s) * QPB + q];
      if (d < fm) { int m_ = poolI[(r1 + s) * QPB + q]; INSERT16(fv, fid, fm, d, m_); }
    }
#pragma unroll
    for (int i = 0; i < KNN; i++) {
      poolF[(r0 + i) * QPB + q] = fv[i];
      poolI[(r0 + i) * QPB + q] = (unsigned short)fid[i];
    }
  }
  __syncthreads();

  // stage B: thread (q, j==0) merges the 4 group results (ascending-m order)
  if (j == 0) {
    for (int g = 1; g < 4; g++) {
      const int rg = (2 * g) * KNN;
      for (int s = 0; s < KNN; s++) {
        float d = poolF[(rg + s) * QPB + q];
        if (d < fm) { int m_ = poolI[(rg + s) * QPB + q]; INSERT16(fv, fid, fm, d, m_); }
      }
    }
#pragma unroll
    for (int i = 0; i < KNN; i++) poolI[i * QPB + q] = (unsigned short)fid[i];
  }
  __syncthreads();

  // gather neighbors (2 per thread) into poolF rows 0..63
#pragma unroll
  for (int kk = 0; kk < 2; kk++) {
    int k = j * 2 + kk;
    int m = poolI[k * QPB + q];
    float4 c = pk[((size_t)b << 13) + m];
    float dx = __fsub_rn(c.x, qx), dy = __fsub_rn(c.y, qy), dz = __fsub_rn(c.z, qz);
    float dsq = __fadd_rn(__fadd_rn(__fmul_rn(dx, dx), __fmul_rn(dy, dy)),
                          __fmul_rn(dz, dz));
    poolF[k * QPB + q] = c.x;
    poolF[(KNN + k) * QPB + q] = c.y;
    poolF[(2 * KNN + k) * QPB + q] = c.z;
    poolF[(3 * KNN + k) * QPB + q] = dsq;
  }
  __syncthreads();

  float nx[KNN], ny[KNN], nz[KNN], nd[KNN];
#pragma unroll
  for (int k = 0; k < KNN; k++) {
    nx[k] = poolF[k * QPB + q];
    ny[k] = poolF[(KNN + k) * QPB + q];
    nz[k] = poolF[(2 * KNN + k) * QPB + q];
    nd[k] = poolF[(3 * KNN + k) * QPB + q];
  }
  float fo[8];
#pragma unroll
  for (int oi = 0; oi < 8; oi++) {
    int o = j * 8 + oi;
    float4 pA = prmL[o], pB = prmL[HDIM + o];
    float basev = fmaf(qz, pA.z, fmaf(qy, pA.y, fmaf(qx, pA.x, pA.w)));
    float mx = -INF;
#pragma unroll
    for (int k = 0; k < KNN; k++) {
      float tv = fmaf(nz[k], pB.z,
                 fmaf(ny[k], pB.y,
                 fmaf(nx[k], pB.x, __fmul_rn(nd[k], pB.w))));
      mx = fmaxf(mx, tv);
    }
    fo[oi] = basev + mx;
  }
  float* feRow = feBuf + (size_t)(b * N_ + n0 + q) * HDIM + j * 8;
  ((float4*)feRow)[0] = make_float4(fo[0], fo[1], fo[2], fo[3]);
  ((float4*)feRow)[1] = make_float4(fo[4], fo[5], fo[6], fo[7]);
}

// ---------------- K2: shortcut GEMM + combine ----------------
__global__ __launch_bounds__(256) void k_out(
    const float* __restrict__ feature, const float* __restrict__ wsM,
    const float* __restrict__ bs, const float* __restrict__ feBuf,
    float* __restrict__ out) {
  const int blk = blockIdx.x;
  const int b  = blk / BLOCKS_PER_B;
  const int n0 = (blk % BLOCKS_PER_B) * QPB;
  const int t = threadIdx.x;
  const int q = t & 63;
  const int jj = t >> 6;
  __shared__ float featL[DIN][QPB];  // 16 KB
  __shared__ float wsL[DOUT][DIN];   // 32 KB
#pragma unroll
  for (int r = 0; r < DIN; r += 4) {
    int c = r + jj;
    featL[c][q] = feature[(size_t)(b * DIN + c) * N_ + n0 + q];
  }
  for (int i = t; i < DOUT * DIN; i += 256) ((float*)wsL)[i] = wsM[i];
  __syncthreads();
  float f[DIN];
#pragma unroll
  for (int c = 0; c < DIN; c++) f[c] = featL[c][q];
  const float* feRow = feBuf + (size_t)(b * N_ + n0 + q) * HDIM;
  const int o0 = jj * 32;
  for (int oi = 0; oi < 32; oi++) {
    int o = o0 + oi;
    const float4* wr = (const float4*)wsL[o];
    float acc = 0.f;
#pragma unroll
    for (int c4 = 0; c4 < DIN / 4; c4++) {
      float4 w = wr[c4];
      acc = fmaf(w.x, f[4 * c4], acc);
      acc = fmaf(w.y, f[4 * c4 + 1], acc);
      acc = fmaf(w.z, f[4 * c4 + 2], acc);
      acc = fmaf(w.w, f[4 * c4 + 3], acc);
    }
    float r = acc + bs[o] + feRow[o & 63];
    out[(size_t)(b * DOUT + o) * N_ + n0 + q] = r;
  }
}

extern "C" void kernel_launch(void* const* d_in, const int* in_sizes, int n_in,
                              void* d_out, int out_size, void* d_ws, size_t ws_size,
                              hipStream_t stream) {
  const float* xyz     = (const float*)d_in[0];
  const float* feature = (const float*)d_in[1];
  const float* w1 = (const float*)d_in[2];
  const float* b1 = (const float*)d_in[3];
  const float* w2 = (const float*)d_in[4];
  const float* b2 = (const float*)d_in[5];
  const float* w3 = (const float*)d_in[6];
  const float* b3 = (const float*)d_in[7];
  const float* wsM = (const float*)d_in[8];
  const float* bs  = (const float*)d_in[9];
  float* out = (float*)d_out;

  // workspace: [0,8KB) prm, [8KB, 8KB+512KB) packed pk, then feBuf (8MB)
  float4* prm  = (float4*)d_ws;
  float4* pkB  = (float4*)((char*)d_ws + 8192);
  float* feBuf = (float*)((char*)d_ws + 8192 + (size_t)B_ * N_ * 16);

  hipLaunchKernelGGL(k_prep, dim3(128), dim3(256), 0, stream,
                     xyz, w1, b1, w2, b2, w3, b3, pkB, prm);
  hipLaunchKernelGGL(k_knn_fe, dim3(B_ * BLOCKS_PER_B), dim3(NTHR), 0, stream,
                     pkB, prm, feBuf);
  hipLaunchKernelGGL(k_out, dim3(B_ * BLOCKS_PER_B), dim3(256), 0, stream,
                     feature, wsM, bs, feBuf, out);
}

// Round 4
// 286.440 us; speedup vs baseline: 2.7342x; 1.0529x over previous
//
#include <hip/hip_runtime.h>

#define B_ 4
#define N_ 8192
#define DIN 64
#define HDIM 64
#define DOUT 128
#define KNN 16
#define QPB 64               // queries per block (= lanes per wave)
#define PART 8               // partner waves per query block
#define NTHR (QPB * PART)    // 512 threads / block
#define CHUNK (N_ / PART)    // 1024 candidates per thread
#define CAP 16               // deferred-insert buffer slots per thread
#define BLOCKS_PER_B (N_ / QPB)  // 128

// ---------------- K_prep: pack (x,y,z,sq) + compose affine params ----------------
__global__ __launch_bounds__(256) void k_prep(
    const float* __restrict__ xyz,
    const float* __restrict__ w1, const float* __restrict__ b1,
    const float* __restrict__ w2, const float* __restrict__ b2,
    const float* __restrict__ w3, const float* __restrict__ b3,
    float4* __restrict__ pk, float4* __restrict__ prm) {
  const int blk = blockIdx.x, t = threadIdx.x;
  const int b = blk >> 5;
  const int m = ((blk & 31) << 8) + t;
  const float* xb = xyz + (size_t)b * 3 * N_;
  float x = xb[m], y = xb[N_ + m], z = xb[2 * N_ + m];
  float sq = __fadd_rn(__fadd_rn(__fmul_rn(x, x), __fmul_rn(y, y)), __fmul_rn(z, z));
  pk[((size_t)b << 13) + m] = make_float4(x, y, z, sq);

  if (blk == 0) {
    __shared__ float M2[HDIM][10];
    __shared__ float bb[HDIM];
    const int o = t;
    if (o < HDIM) {
      float r[10];
#pragma unroll
      for (int c = 0; c < 10; c++) r[c] = 0.f;
      float s = b2[o];
      for (int l = 0; l < HDIM; l++) {
        float w = w2[o * HDIM + l];
#pragma unroll
        for (int c = 0; c < 10; c++) r[c] = fmaf(w, w1[l * 10 + c], r[c]);
        s = fmaf(w, b1[l], s);
      }
#pragma unroll
      for (int c = 0; c < 10; c++) M2[o][c] = r[c];
      bb[o] = s;
    }
    __syncthreads();
    if (o < HDIM) {
      float r3[10];
#pragma unroll
      for (int c = 0; c < 10; c++) r3[c] = 0.f;
      float bc = b3[o];
      for (int l = 0; l < HDIM; l++) {
        float w = w3[o * HDIM + l];
#pragma unroll
        for (int c = 0; c < 10; c++) r3[c] = fmaf(w, M2[l][c], r3[c]);
        bc = fmaf(w, bb[l], bc);
      }
      prm[o]      = make_float4(r3[0] - r3[6], r3[1] - r3[7], r3[2] - r3[8], bc);
      prm[64 + o] = make_float4(r3[3] + r3[6], r3[4] + r3[7], r3[5] + r3[8], r3[9]);
    }
  }
}

// replace-max insert into unsorted top-16 kept in registers (fully unrolled)
#define INSERT16(VARR, IARR, VMAX, DVAL, MIDX)                    \
  {                                                               \
    bool done = false;                                            \
    _Pragma("unroll") for (int _i = 0; _i < KNN; _i++) {          \
      bool hit = (!done) && (VARR[_i] == VMAX);                   \
      if (hit) { VARR[_i] = (DVAL); IARR[_i] = (MIDX); }          \
      done = done | hit;                                          \
    }                                                             \
    float _a = fmaxf(fmaxf(fmaxf(VARR[0], VARR[1]), fmaxf(VARR[2], VARR[3])),   \
                     fmaxf(fmaxf(VARR[4], VARR[5]), fmaxf(VARR[6], VARR[7])));  \
    float _b = fmaxf(fmaxf(fmaxf(VARR[8], VARR[9]), fmaxf(VARR[10], VARR[11])), \
                     fmaxf(fmaxf(VARR[12], VARR[13]), fmaxf(VARR[14], VARR[15])));\
    VMAX = fmaxf(_a, _b);                                         \
  }

#define MAX16(VARR, VMAX)                                         \
  {                                                               \
    float _a = fmaxf(fmaxf(fmaxf(VARR[0], VARR[1]), fmaxf(VARR[2], VARR[3])),   \
                     fmaxf(fmaxf(VARR[4], VARR[5]), fmaxf(VARR[6], VARR[7])));  \
    float _b = fmaxf(fmaxf(fmaxf(VARR[8], VARR[9]), fmaxf(VARR[10], VARR[11])), \
                     fmaxf(fmaxf(VARR[12], VARR[13]), fmaxf(VARR[14], VARR[15])));\
    VMAX = fmaxf(_a, _b);                                         \
  }

// drain deferred buffer through INSERT16, publish tau, tighten gate
#define FLUSH()                                                   \
  {                                                               \
    for (int c_ = 0; c_ < cnt; c_++) {                            \
      float fd_ = poolF[c_ * NTHR + t];                           \
      int fm_ = poolI[c_ * NTHR + t];                             \
      if (fd_ < vmax) { INSERT16(v, id, vmax, fd_, fm_); }        \
    }                                                             \
    cnt = 0;                                                      \
    atomicMin(&tau[q], __float_as_uint(vmax));                    \
    gate = fminf(vmax, __uint_as_float(tau[q]));                  \
  }

// ---------------- K1: fused kNN + fe + shortcut + output ----------------
// block: 64 queries x 8 partner waves; wave j scans candidates [j*1024,(j+1)*1024)
// via wave-uniform loads from packed pk (L2-resident). Tail: tree-merge top-16,
// gather neighbors, fe (composed affine + maxpool), then shortcut GEMM + store.
__global__ __launch_bounds__(NTHR, 4) void k_knn_fe(
    const float4* __restrict__ pk, const float4* __restrict__ prm,
    const float* __restrict__ feature, const float* __restrict__ wsM,
    const float* __restrict__ bs, float* __restrict__ out) {
  const int blk = blockIdx.x;
  const int b  = blk / BLOCKS_PER_B;
  const int n0 = (blk % BLOCKS_PER_B) * QPB;
  const int t = threadIdx.x;
  const int q = t & 63;
  const int j = __builtin_amdgcn_readfirstlane(t >> 6);  // wave-uniform partner id

  __shared__ unsigned tau[QPB];
  __shared__ float4 prmL[2 * HDIM];
  // 48 KB pool, time-multiplexed:
  //  scan:   poolF[c*512+t] (32KB), poolI[c*512+t] (16KB)      (c < CAP)
  //  merge:  rows r<128: poolF[r*64+q], poolI[r*64+q]
  //  gather: rows r<64 of poolF = neighbor x/y/z/dsq
  //  epilogue: poolF = ws[128][64], poolI-as-float = feature tile [64][64]
  __shared__ alignas(16) float poolF[CAP * NTHR];
  __shared__ alignas(16) unsigned short poolI[CAP * NTHR];

  if (t < QPB) tau[t] = 0x7f800000u;  // +inf
  for (int i = t; i < 2 * HDIM; i += NTHR) prmL[i] = prm[i];

  const float4 qv = pk[((size_t)b << 13) + n0 + q];
  const float qx = qv.x, qy = qv.y, qz = qv.z, qs = qv.w;

  const float INF = __uint_as_float(0x7f800000u);
  float v[KNN]; int id[KNN];
  float vmax, gate;
  int cnt = 0;
  __syncthreads();

  const float4* pj = pk + ((size_t)b << 13) + j * CHUNK;

  // warm start: first 16 candidates fill the list directly (no gating, no flush
  // storm; list order = scan order so tie semantics match the gated path)
  {
    float4 c[KNN];
#pragma unroll
    for (int e = 0; e < KNN; e++) c[e] = pj[e];
#pragma unroll
    for (int e = 0; e < KNN; e++) {
      float dot = fmaf(c[e].z, qz, fmaf(c[e].y, qy, __fmul_rn(c[e].x, qx)));
      v[e] = __fsub_rn(__fadd_rn(qs, c[e].w), __fmul_rn(2.0f, dot));
      id[e] = j * CHUNK + e;
    }
    MAX16(v, vmax);
    atomicMin(&tau[q], __float_as_uint(vmax));   // publish early so partners gate
    gate = fminf(vmax, __uint_as_float(tau[q]));
  }

  for (int u0 = KNN; u0 < CHUNK; u0 += 8) {
    if (__any(cnt > CAP - 8)) { FLUSH(); }
    gate = fminf(gate, __uint_as_float(tau[q]));  // pick up partners' progress
    float4 c[8];
#pragma unroll
    for (int e = 0; e < 8; e++) c[e] = pj[u0 + e];  // 8 independent uniform loads
#pragma unroll
    for (int e = 0; e < 8; e++) {
      // match reference rounding: dot as fma chain, sums as plain mul+add
      float dot = fmaf(c[e].z, qz, fmaf(c[e].y, qy, __fmul_rn(c[e].x, qx)));
      float d = __fsub_rn(__fadd_rn(qs, c[e].w), __fmul_rn(2.0f, dot));
      if (d < gate) {  // cheap predicated push
        poolF[cnt * NTHR + t] = d;
        poolI[cnt * NTHR + t] = (unsigned short)(j * CHUNK + u0 + e);
        cnt++;
      }
    }
  }
  FLUSH();
  __syncthreads();

  // publish per-thread lists: rows j*16+i (ascending-m order across j)
#pragma unroll
  for (int i = 0; i < KNN; i++) {
    poolF[(j * KNN + i) * QPB + q] = v[i];
    poolI[(j * KNN + i) * QPB + q] = (unsigned short)id[i];
  }
  __syncthreads();

  float fv[KNN]; int fid[KNN]; float fm = INF;
  // stage A: wave j<4 merges partners (2j, 2j+1) -> rows (2j)*16
  if (j < 4) {
    const int l0 = (2 * j) * KNN, r1 = (2 * j + 1) * KNN;
#pragma unroll
    for (int i = 0; i < KNN; i++) {
      fv[i] = poolF[(l0 + i) * QPB + q];
      fid[i] = poolI[(l0 + i) * QPB + q];
    }
    MAX16(fv, fm);
    for (int s = 0; s < KNN; s++) {
      float d = poolF[(r1 + s) * QPB + q];
      if (d < fm) { int m_ = poolI[(r1 + s) * QPB + q]; INSERT16(fv, fid, fm, d, m_); }
    }
#pragma unroll
    for (int i = 0; i < KNN; i++) {
      poolF[(l0 + i) * QPB + q] = fv[i];
      poolI[(l0 + i) * QPB + q] = (unsigned short)fid[i];
    }
  }
  __syncthreads();
  // stage B: wave0: rows0+rows32 ; wave1: rows64+rows96 (ascending order kept)
  if (j < 2) {
    const int l0 = (4 * j) * KNN, r1 = (4 * j + 2) * KNN;
#pragma unroll
    for (int i = 0; i < KNN; i++) {
      fv[i] = poolF[(l0 + i) * QPB + q];
      fid[i] = poolI[(l0 + i) * QPB + q];
    }
    MAX16(fv, fm);
    for (int s = 0; s < KNN; s++) {
      float d = poolF[(r1 + s) * QPB + q];
      if (d < fm) { int m_ = poolI[(r1 + s) * QPB + q]; INSERT16(fv, fid, fm, d, m_); }
    }
#pragma unroll
    for (int i = 0; i < KNN; i++) {
      poolF[(l0 + i) * QPB + q] = fv[i];
      poolI[(l0 + i) * QPB + q] = (unsigned short)fid[i];
    }
  }
  __syncthreads();
  // stage C: wave0 merges rows0 + rows64 -> final ids in poolI rows 0..15
  if (j == 0) {
#pragma unroll
    for (int i = 0; i < KNN; i++) {
      fv[i] = poolF[i * QPB + q];
      fid[i] = poolI[i * QPB + q];
    }
    MAX16(fv, fm);
    for (int s = 0; s < KNN; s++) {
      float d = poolF[(4 * KNN + s) * QPB + q];
      if (d < fm) { int m_ = poolI[(4 * KNN + s) * QPB + q]; INSERT16(fv, fid, fm, d, m_); }
    }
#pragma unroll
    for (int i = 0; i < KNN; i++) poolI[i * QPB + q] = (unsigned short)fid[i];
  }
  __syncthreads();

  // gather neighbors (2 per wave-slot) into poolF rows 0..63
#pragma unroll
  for (int kk = 0; kk < 2; kk++) {
    int k = j * 2 + kk;
    int m = poolI[k * QPB + q];
    float4 c = pk[((size_t)b << 13) + m];
    float dx = __fsub_rn(c.x, qx), dy = __fsub_rn(c.y, qy), dz = __fsub_rn(c.z, qz);
    float dsq = __fadd_rn(__fadd_rn(__fmul_rn(dx, dx), __fmul_rn(dy, dy)),
                          __fmul_rn(dz, dz));
    poolF[k * QPB + q] = c.x;
    poolF[(KNN + k) * QPB + q] = c.y;
    poolF[(2 * KNN + k) * QPB + q] = c.z;
    poolF[(3 * KNN + k) * QPB + q] = dsq;
  }
  __syncthreads();

  float fo[8];
  {
    float nx[KNN], ny[KNN], nz[KNN], nd[KNN];
#pragma unroll
    for (int k = 0; k < KNN; k++) {
      nx[k] = poolF[k * QPB + q];
      ny[k] = poolF[(KNN + k) * QPB + q];
      nz[k] = poolF[(2 * KNN + k) * QPB + q];
      nd[k] = poolF[(3 * KNN + k) * QPB + q];
    }
#pragma unroll
    for (int oi = 0; oi < 8; oi++) {
      int o = j * 8 + oi;
      float4 pA = prmL[o], pB = prmL[HDIM + o];
      float basev = fmaf(qz, pA.z, fmaf(qy, pA.y, fmaf(qx, pA.x, pA.w)));
      float mx = -INF;
#pragma unroll
      for (int k = 0; k < KNN; k++) {
        float tv = fmaf(nz[k], pB.z,
                   fmaf(ny[k], pB.y,
                   fmaf(nx[k], pB.x, __fmul_rn(nd[k], pB.w))));
        mx = fmaxf(mx, tv);
      }
      fo[oi] = basev + mx;
    }
  }
  __syncthreads();  // pool free -> reuse for ws + feature tile

  // stage ws [128][64] into poolF (32 KB), feature tile [64][64] into poolI (16 KB)
  float* wsL = poolF;
  float* feL = (float*)poolI;
  for (int i = t; i < DOUT * DIN; i += NTHR) wsL[i] = wsM[i];
#pragma unroll
  for (int r = 0; r < 8; r++) {
    int c = j * 8 + r;
    feL[c * QPB + q] = feature[(size_t)(b * DIN + c) * N_ + n0 + q];
  }
  __syncthreads();

  // shortcut GEMM: wave j computes outputs o=j*8..j*8+7 and o+64 for its query q
  float acc[16];
#pragma unroll
  for (int oi = 0; oi < 16; oi++) acc[oi] = 0.f;
  for (int c4 = 0; c4 < DIN / 4; c4++) {
    float f0 = feL[(4 * c4 + 0) * QPB + q];
    float f1 = feL[(4 * c4 + 1) * QPB + q];
    float f2 = feL[(4 * c4 + 2) * QPB + q];
    float f3 = feL[(4 * c4 + 3) * QPB + q];
#pragma unroll
    for (int oi = 0; oi < 16; oi++) {
      int o = (oi < 8) ? (j * 8 + oi) : (64 + j * 8 + oi - 8);
      float4 w = ((const float4*)(wsL + o * DIN))[c4];  // wave-uniform broadcast
      acc[oi] = fmaf(w.x, f0, acc[oi]);
      acc[oi] = fmaf(w.y, f1, acc[oi]);
      acc[oi] = fmaf(w.z, f2, acc[oi]);
      acc[oi] = fmaf(w.w, f3, acc[oi]);
    }
  }
  float* ob = out + (size_t)b * DOUT * N_ + n0 + q;
#pragma unroll
  for (int oi = 0; oi < 16; oi++) {
    int o = (oi < 8) ? (j * 8 + oi) : (64 + j * 8 + oi - 8);
    ob[(size_t)o * N_] = acc[oi] + bs[o] + fo[oi & 7];
  }
}

extern "C" void kernel_launch(void* const* d_in, const int* in_sizes, int n_in,
                              void* d_out, int out_size, void* d_ws, size_t ws_size,
                              hipStream_t stream) {
  const float* xyz     = (const float*)d_in[0];
  const float* feature = (const float*)d_in[1];
  const float* w1 = (const float*)d_in[2];
  const float* b1 = (const float*)d_in[3];
  const float* w2 = (const float*)d_in[4];
  const float* b2 = (const float*)d_in[5];
  const float* w3 = (const float*)d_in[6];
  const float* b3 = (const float*)d_in[7];
  const float* wsM = (const float*)d_in[8];
  const float* bs  = (const float*)d_in[9];
  float* out = (float*)d_out;

  // workspace: [0,8KB) prm, [8KB, 8KB+512KB) packed pk
  float4* prm = (float4*)d_ws;
  float4* pkB = (float4*)((char*)d_ws + 8192);

  hipLaunchKernelGGL(k_prep, dim3(128), dim3(256), 0, stream,
                     xyz, w1, b1, w2, b2, w3, b3, pkB, prm);
  hipLaunchKernelGGL(k_knn_fe, dim3(B_ * BLOCKS_PER_B), dim3(NTHR), 0, stream,
                     pkB, prm, feature, wsM, bs, out);
}